// Round 7
// baseline (135.219 us; speedup 1.0000x reference)
//
#include <hip/hip_runtime.h>

// LocBlock2dNT: x (64,64,64,64) f32, w (256,64,16,16,16) f32
// out (64,256,16,16) f32 = relu( einsum('ncpqf,ocpqf->nopq', patches, w) / 32 )
//
// Pass 1 (prep): unfold+convert x -> xT bf16, [pq][c][koct2][n64][k8]
//   -> A-fragments are lane-contiguous 16-B loads (256-B runs per instr).
// Pass 2 (gemm): block = (p, q-pair, o-half), grid 256. NO LDS, NO barriers:
//   every wave is an autonomous 2-deep software pipeline. A and B are loaded
//   directly into MFMA fragment registers; counted vmcnt(8) + sched_barrier
//   pins the prefetch distance. Output: direct scattered 4-B stores.

typedef short bf16x8 __attribute__((ext_vector_type(8)));
typedef short bf16x4 __attribute__((ext_vector_type(4)));
typedef float f32x4  __attribute__((ext_vector_type(4)));

__device__ __forceinline__ short f2bf(float f) {
    union { float f; unsigned u; } v; v.f = f;
    return (short)((v.u + 0x7FFFu + ((v.u >> 16) & 1u)) >> 16);   // RNE
}

__device__ __forceinline__ bf16x8 pack8(f32x4 a, f32x4 b) {
    bf16x8 r;
    r[0] = f2bf(a[0]); r[1] = f2bf(a[1]); r[2] = f2bf(a[2]); r[3] = f2bf(a[3]);
    r[4] = f2bf(b[0]); r[5] = f2bf(b[1]); r[6] = f2bf(b[2]); r[7] = f2bf(b[3]);
    return r;
}

// ---------------------------------------------------------------- pass 1
__global__ __launch_bounds__(256)
void prep_unfold(const float* __restrict__ x, short* __restrict__ xT) {
    __shared__ __align__(16) char tile[16 * 2056];
    const int bid = blockIdx.x;
    const int p = bid >> 6, c = bid & 63;
    const int t = (int)threadIdx.x;

#pragma unroll
    for (int it = 0; it < 16; ++it) {
        const int id = it * 256 + t;
        const int n = id >> 6, fr = (id >> 4) & 3, cq = id & 15;
        const f32x4 v = *(const f32x4*)(x + (size_t)n * 262144u
                                          + (size_t)c * 4096u
                                          + (size_t)(4 * p + fr) * 64u
                                          + (size_t)(cq * 4));
        bf16x4 b; b[0] = f2bf(v[0]); b[1] = f2bf(v[1]);
                  b[2] = f2bf(v[2]); b[3] = f2bf(v[3]);
        *(bf16x4*)(tile + cq * 2056 + (fr >> 1) * 1024 + n * 16
                        + (fr & 1) * 8) = b;
    }
    __syncthreads();

#pragma unroll
    for (int it = 0; it < 8; ++it) {
        const int id = it * 256 + t;
        const int q = id >> 7, s = id & 127;
        const int koct = s >> 6, n = s & 63;
        const bf16x8 v = *(const bf16x8*)(tile + q * 2056 + koct * 1024 + n * 16);
        *(bf16x8*)(xT + (size_t)(p * 16 + q) * 65536u + (size_t)c * 1024u
                      + (size_t)koct * 512u + (size_t)n * 8u) = v;
    }
}

// ---------------------------------------------------------------- pass 2
__global__ __launch_bounds__(512)
void locblock_gemm(const short* __restrict__ xT, const float* __restrict__ w,
                   float* __restrict__ out) {
    const int hw = blockIdx.x;
    const int lb = (hw & 7) * 32 + (hw >> 3);        // XCD swizzle, bijective
    const int p  = lb >> 4;
    const int q2 = (lb >> 1) & 7;                    // q = 2*q2 + qw
    const int oh = lb & 1;

    const int tid  = (int)threadIdx.x;
    const int lane = tid & 63;
    const int wv   = tid >> 6;
    const int l15  = lane & 15;
    const int kq   = lane >> 4;
    const int qw   = wv & 1;                         // wave's q
    const int nc   = wv >> 1;                        // wave's o-quarter (32 o)

    // ---- A fragment source: lane-contiguous bf16 (advance 2048/step) ----
    // frag: row n = mf*16 + l15, k32 = kq*8 + j  (c_off = kq>>1, koct = kq&1)
    const short* asrc = xT + (size_t)(p * 16 + q2 * 2 + qw) * 65536u
                           + (size_t)(kq >> 1) * 1024u + (size_t)(kq & 1) * 512u
                           + (size_t)l15 * 8u;

    // ---- B fragment sources: per-lane 16-B chunk pair (u1, u1+1) ----
    // chunk u = c_off*8 + h8 within the (o, 2c, p, 2q) 256-B region;
    // u1 = (kq>>1)*8 + qw*4 + (kq&1)*2 -> frag k32 = kq*8 + j  (verified r6)
    const int u1 = (kq >> 1) * 8 + qw * 4 + (kq & 1) * 2;
    const float* bsrc[2];
#pragma unroll
    for (int nf = 0; nf < 2; ++nf) {
        const int o = oh * 128 + nc * 32 + nf * 16 + l15;
        bsrc[nf] = w + (size_t)o * 262144u + (size_t)(u1 >> 3) * 4096u
                     + (size_t)p * 256u + (size_t)(q2 * 32)
                     + (size_t)((u1 & 7) * 4);       // +4 floats = chunk u1+1
    }

    f32x4 acc[4][2];
#pragma unroll
    for (int mf = 0; mf < 4; ++mf)
#pragma unroll
        for (int nf = 0; nf < 2; ++nf)
            acc[mf][nf] = (f32x4){0.f, 0.f, 0.f, 0.f};

    bf16x8 as0[4], as1[4];
    f32x4  bs0[2][2], bs1[2][2];

#define ISSUE(AS, BS, T)                                                      \
    _Pragma("unroll") for (int nf = 0; nf < 2; ++nf) {                        \
        BS[nf][0] = *(const f32x4*)(bsrc[nf] + (size_t)(T) * 8192u);          \
        BS[nf][1] = *(const f32x4*)(bsrc[nf] + (size_t)(T) * 8192u + 4);      \
    }                                                                         \
    _Pragma("unroll") for (int mf = 0; mf < 4; ++mf)                          \
        AS[mf] = *(const bf16x8*)(asrc + (size_t)(T) * 2048u + mf * 128);

#define COMPUTE(AS, BS)                                                       \
    { bf16x8 bv0 = pack8(BS[0][0], BS[0][1]);                                 \
      bf16x8 bv1 = pack8(BS[1][0], BS[1][1]);                                 \
      _Pragma("unroll") for (int mf = 0; mf < 4; ++mf) {                      \
          acc[mf][0] = __builtin_amdgcn_mfma_f32_16x16x32_bf16(               \
              AS[mf], bv0, acc[mf][0], 0, 0, 0);                              \
          acc[mf][1] = __builtin_amdgcn_mfma_f32_16x16x32_bf16(               \
              AS[mf], bv1, acc[mf][1], 0, 0, 0);                              \
      } }

    // ---- barrier-free 2-deep pipeline over 32 K-steps (8 loads/set) ----
    ISSUE(as0, bs0, 0);
    ISSUE(as1, bs1, 1);
#pragma unroll 1
    for (int t = 0; t < 30; t += 2) {
        asm volatile("s_waitcnt vmcnt(8)" ::: "memory");   // set0 landed
        __builtin_amdgcn_sched_barrier(0);
        COMPUTE(as0, bs0);
        ISSUE(as0, bs0, t + 2);
        asm volatile("s_waitcnt vmcnt(8)" ::: "memory");   // set1 landed
        __builtin_amdgcn_sched_barrier(0);
        COMPUTE(as1, bs1);
        ISSUE(as1, bs1, t + 3);
    }
    asm volatile("s_waitcnt vmcnt(8)" ::: "memory");
    __builtin_amdgcn_sched_barrier(0);
    COMPUTE(as0, bs0);                                     // t = 30
    asm volatile("s_waitcnt vmcnt(0)" ::: "memory");
    __builtin_amdgcn_sched_barrier(0);
    COMPUTE(as1, bs1);                                     // t = 31

#undef ISSUE
#undef COMPUTE

    // ---- epilogue: relu-scale, direct scattered stores to out[n][o][pq] ----
    const float scale = 0.03125f;                    // 1/sqrt(16*64)
    const int pq = p * 16 + q2 * 2 + qw;
#pragma unroll
    for (int mf = 0; mf < 4; ++mf)
#pragma unroll
        for (int nf = 0; nf < 2; ++nf) {
            const int o = oh * 128 + nc * 32 + nf * 16 + l15;
            float* ob = out + (size_t)(mf * 16 + kq * 4) * 65536u
                            + (size_t)o * 256u + pq;
#pragma unroll
            for (int j = 0; j < 4; ++j)
                ob[(size_t)j * 65536u] = fmaxf(acc[mf][nf][j] * scale, 0.0f);
        }
}

extern "C" void kernel_launch(void* const* d_in, const int* in_sizes, int n_in,
                              void* d_out, int out_size, void* d_ws, size_t ws_size,
                              hipStream_t stream) {
    const float* x = (const float*)d_in[0];
    const float* w = (const float*)d_in[1];
    float* out = (float*)d_out;
    short* xT  = (short*)d_ws;                       // 32 MB bf16
    prep_unfold  <<<dim3(1024), dim3(256), 0, stream>>>(x, xT);
    locblock_gemm<<<dim3(256),  dim3(512), 0, stream>>>(xT, w, out);
}

// Round 8
// 100.766 us; speedup vs baseline: 1.3419x; 1.3419x over previous
//
#include <hip/hip_runtime.h>

// LocBlock2dNT: x (64,64,64,64) f32, w (256,64,16,16,16) f32
// out (64,256,16,16) f32 = relu( einsum('ncpqf,ocpqf->nopq', patches, w) / 32 )
//
// Pass 1 (prep): unfold+convert x -> xT bf16, [pq][c][koct2][n64][k8].
// Pass 2 (gemm): block = (p, q-pair, o-quarter), grid 512 = 2 blocks/CU
//   (desynchronized co-residents cover each other's barrier/compute gaps).
//   A (xT): gload_lds 1-KB runs, skewed LDS strides; B (w): gload_lds 128-B
//   runs, XOR source swizzle. 3-deep, vmcnt(6). -> ws2 [pq][o][n].
// Pass 3 (post): transpose ws2 -> out [n][o][pq] (coalesced).

typedef short bf16x8 __attribute__((ext_vector_type(8)));
typedef short bf16x4 __attribute__((ext_vector_type(4)));
typedef float f32x4  __attribute__((ext_vector_type(4)));

__device__ __forceinline__ short f2bf(float f) {
    union { float f; unsigned u; } v; v.f = f;
    return (short)((v.u + 0x7FFFu + ((v.u >> 16) & 1u)) >> 16);   // RNE
}

__device__ __forceinline__ bf16x8 pack8(f32x4 a, f32x4 b) {
    bf16x8 r;
    r[0] = f2bf(a[0]); r[1] = f2bf(a[1]); r[2] = f2bf(a[2]); r[3] = f2bf(a[3]);
    r[4] = f2bf(b[0]); r[5] = f2bf(b[1]); r[6] = f2bf(b[2]); r[7] = f2bf(b[3]);
    return r;
}

__device__ __forceinline__ void gload16(const void* g, void* l) {
    __builtin_amdgcn_global_load_lds(
        (const __attribute__((address_space(1))) void*)g,
        (__attribute__((address_space(3))) void*)l, 16, 0, 0);
}

// ---------------------------------------------------------------- pass 1
__global__ __launch_bounds__(256)
void prep_unfold(const float* __restrict__ x, short* __restrict__ xT) {
    __shared__ __align__(16) char tile[16 * 2056];
    const int bid = blockIdx.x;
    const int p = bid >> 6, c = bid & 63;
    const int t = (int)threadIdx.x;

#pragma unroll
    for (int it = 0; it < 16; ++it) {
        const int id = it * 256 + t;
        const int n = id >> 6, fr = (id >> 4) & 3, cq = id & 15;
        const f32x4 v = *(const f32x4*)(x + (size_t)n * 262144u
                                          + (size_t)c * 4096u
                                          + (size_t)(4 * p + fr) * 64u
                                          + (size_t)(cq * 4));
        bf16x4 b; b[0] = f2bf(v[0]); b[1] = f2bf(v[1]);
                  b[2] = f2bf(v[2]); b[3] = f2bf(v[3]);
        *(bf16x4*)(tile + cq * 2056 + (fr >> 1) * 1024 + n * 16
                        + (fr & 1) * 8) = b;
    }
    __syncthreads();

#pragma unroll
    for (int it = 0; it < 8; ++it) {
        const int id = it * 256 + t;
        const int q = id >> 7, s = id & 127;
        const int koct = s >> 6, n = s & 63;
        const bf16x8 v = *(const bf16x8*)(tile + q * 2056 + koct * 1024 + n * 16);
        *(bf16x8*)(xT + (size_t)(p * 16 + q) * 65536u + (size_t)c * 1024u
                      + (size_t)koct * 512u + (size_t)n * 8u) = v;
    }
}

// ---------------------------------------------------------------- pass 2
#define A_BYTES 8448                                  // 2*2*2*64*16 + skew
#define STAGE_BYTES 24832                             // A 8448 + B 16384
__global__ __launch_bounds__(512, 4)
void locblock_gemm(const short* __restrict__ xT, const float* __restrict__ w,
                   float* __restrict__ ws2) {
    __shared__ __align__(16) char smem[3][STAGE_BYTES];   // 72.75 KB

    const int hw = blockIdx.x;
    const int lb = (hw & 7) * 64 + (hw >> 3);        // XCD swizzle, bijective
    const int p  = lb >> 5;                          // 0..15
    const int q2 = (lb >> 2) & 7;                    // q = 2*q2 + qw
    const int oq = lb & 3;                           // o-quarter (64 o's)

    const int tid  = (int)threadIdx.x;
    const int lane = tid & 63;
    const int wv   = tid >> 6;
    const int l15  = lane & 15;
    const int kq   = lane >> 4;
    const int qw   = wv & 1;                         // wave's q of the pair
    const int nc   = wv >> 1;                        // wave's 16-o group

    // ---- A staging: 512 chunks/step, 1 per thread ----
    // tid -> (qin, cin, koct, n); LDS dest skewed: qin*4224+cin*2112+koct*1056
    const int aqin = tid >> 8, acin = (tid >> 7) & 1;
    const int akoct = (tid >> 6) & 1, an = tid & 63;
    const short* asrc = xT + (size_t)(p * 16 + q2 * 2 + aqin) * 65536u
                           + (size_t)acin * 1024u + (size_t)akoct * 512u
                           + (size_t)an * 8u;        // +2048 shorts per step
    const int adst = aqin * 4224 + acin * 2112 + akoct * 1056 + an * 16;

    // ---- B staging: 1024 chunks/step, 2 per thread; XOR ^(ol&15) on src ----
    const float* bsrc[2];
#pragma unroll
    for (int j = 0; j < 2; ++j) {
        const int id = j * 512 + tid;
        const int ol = id >> 4, s = id & 15;
        const int u = s ^ (ol & 15);                 // u = c_off*8 + h8
        bsrc[j] = w + (size_t)(oq * 64 + ol) * 262144u + (size_t)(u >> 3) * 4096u
                    + (size_t)p * 256u + (size_t)(q2 * 32) + (size_t)((u & 7) * 4);
    }

    // ---- fragment LDS byte offsets ----
    int aoff[4];
#pragma unroll
    for (int mf = 0; mf < 4; ++mf)
        aoff[mf] = qw * 4224 + (kq >> 1) * 2112 + (kq & 1) * 1056
                 + (mf * 16 + l15) * 16;
    const int u1 = (kq >> 1) * 8 + qw * 4 + (kq & 1) * 2;
    const int ol0 = nc * 16 + l15;
    const int boff0 = A_BYTES + ol0 * 256 + ((u1       ^ l15) * 16);
    const int boff1 = A_BYTES + ol0 * 256 + (((u1 + 1) ^ l15) * 16);

    f32x4 acc[4];
#pragma unroll
    for (int mf = 0; mf < 4; ++mf)
        acc[mf] = (f32x4){0.f, 0.f, 0.f, 0.f};

    auto stage = [&](int t, int buf) {
        char* base = smem[buf];
        gload16(asrc + (size_t)t * 2048u, base + adst);            // A: 1
#pragma unroll
        for (int j = 0; j < 2; ++j)                                 // B: 2
            gload16(bsrc[j] + (size_t)t * 8192u,
                    base + A_BYTES + j * 8192 + wv * 1024);
    };

    auto compute = [&](int buf) {
        const char* Lb = smem[buf];
        bf16x8 bv = pack8(*(const f32x4*)(Lb + boff0),
                          *(const f32x4*)(Lb + boff1));
#pragma unroll
        for (int mf = 0; mf < 4; ++mf) {
            bf16x8 av = *(const bf16x8*)(Lb + aoff[mf]);
            acc[mf] = __builtin_amdgcn_mfma_f32_16x16x32_bf16(
                av, bv, acc[mf], 0, 0, 0);
        }
    };

    // ---- 3-deep pipeline over 32 K-steps (3 loads/thread per stage) ----
    stage(0, 0);
    stage(1, 1);
    stage(2, 2);
#pragma unroll 1
    for (int t = 0; t < 29; ++t) {
        const int buf = t % 3;
        asm volatile("s_waitcnt vmcnt(6)" ::: "memory");   // stage t landed
        __builtin_amdgcn_s_barrier();
        compute(buf);
        asm volatile("s_waitcnt lgkmcnt(0)" ::: "memory"); // reads retired
        __builtin_amdgcn_s_barrier();
        stage(t + 3, buf);
    }
    asm volatile("s_waitcnt vmcnt(6)" ::: "memory");
    __builtin_amdgcn_s_barrier();
    compute(2);                                            // t = 29
    asm volatile("s_waitcnt vmcnt(3)" ::: "memory");
    __builtin_amdgcn_s_barrier();
    compute(0);                                            // t = 30
    asm volatile("s_waitcnt vmcnt(0)" ::: "memory");
    __builtin_amdgcn_s_barrier();
    compute(1);                                            // t = 31

    // ---- epilogue: relu-scale -> ws2[pq][o][n] (16-B contiguous) ----
    const float scale = 0.03125f;                    // 1/sqrt(16*64)
    const int pq = p * 16 + q2 * 2 + qw;
    const int o  = oq * 64 + nc * 16 + l15;
#pragma unroll
    for (int mf = 0; mf < 4; ++mf) {
        const int n0 = mf * 16 + kq * 4;             // C/D row = kq*4 + j
        f32x4 r;
#pragma unroll
        for (int j = 0; j < 4; ++j)
            r[j] = fmaxf(acc[mf][j] * scale, 0.0f);
        *(f32x4*)(ws2 + (size_t)pq * 16384u + (size_t)o * 64u + n0) = r;
    }
}

// ---------------------------------------------------------------- pass 3
__global__ __launch_bounds__(256)
void finish_transpose(const float* __restrict__ ws2, float* __restrict__ out) {
    __shared__ float tile[256 * 68];
    const int o = blockIdx.x;
    const int t = (int)threadIdx.x;

#pragma unroll
    for (int it = 0; it < 16; ++it) {
        const int chunk = it * 256 + t;
        const int pq = chunk >> 4, ng = chunk & 15;
        const f32x4 v = *(const f32x4*)(ws2 + (size_t)pq * 16384u
                                            + (size_t)o * 64u + ng * 4);
        *(f32x4*)&tile[pq * 68 + ng * 4] = v;
    }
    __syncthreads();

    const int n = t >> 2, pqq = t & 3;
#pragma unroll
    for (int i = 0; i < 16; ++i) {
        const int pq0 = i * 16 + pqq * 4;
        f32x4 r;
#pragma unroll
        for (int k = 0; k < 4; ++k)
            r[k] = tile[(pq0 + k) * 68 + n];
        *(f32x4*)(out + (size_t)n * 65536u + (size_t)o * 256u + pq0) = r;
    }
}

extern "C" void kernel_launch(void* const* d_in, const int* in_sizes, int n_in,
                              void* d_out, int out_size, void* d_ws, size_t ws_size,
                              hipStream_t stream) {
    const float* x = (const float*)d_in[0];
    const float* w = (const float*)d_in[1];
    float* out = (float*)d_out;
    short* xT  = (short*)d_ws;                              // 32 MB bf16
    float* ws2 = (float*)((char*)d_ws + (33554432));        // 16 MB f32
    prep_unfold     <<<dim3(1024), dim3(256), 0, stream>>>(x, xT);
    locblock_gemm   <<<dim3(512),  dim3(512), 0, stream>>>(xT, w, ws2);
    finish_transpose<<<dim3(256),  dim3(256), 0, stream>>>(ws2, out);
}

// Round 9
// 95.544 us; speedup vs baseline: 1.4153x; 1.0546x over previous
//
#include <hip/hip_runtime.h>

// LocBlock2dNT: x (64,64,64,64) f32, w (256,64,16,16,16) f32
// out (64,256,16,16) f32 = relu( einsum('ncpqf,ocpqf->nopq', patches, w) / 32 )
//
// SINGLE kernel: block = (p, q-pair, o-half), grid 256.
//   GEMM M=64(n) x N=128(o) x K=1024 per (p,q), two q's per block (one per
//   wave-pair). w staged as 128-B contiguous runs, x as 32-B runs, via
//   global_load_lds (3-deep, counted vmcnt(12)). XOR source-swizzle on both
//   tiles (LDS dest linear, rule: gload_lds writes base+lane*16).
//   Epilogue: relu-scale + direct scattered 4-B stores to out[n][o][pq]
//   (L2 merges; ~23 MB WRITE_SIZE measured in r2).

typedef short bf16x8 __attribute__((ext_vector_type(8)));
typedef float f32x4  __attribute__((ext_vector_type(4)));

__device__ __forceinline__ short f2bf(float f) {
    union { float f; unsigned u; } v; v.f = f;
    return (short)((v.u + 0x7FFFu + ((v.u >> 16) & 1u)) >> 16);   // RNE
}

__device__ __forceinline__ bf16x8 pack8(f32x4 a, f32x4 b) {
    bf16x8 r;
    r[0] = f2bf(a[0]); r[1] = f2bf(a[1]); r[2] = f2bf(a[2]); r[3] = f2bf(a[3]);
    r[4] = f2bf(b[0]); r[5] = f2bf(b[1]); r[6] = f2bf(b[2]); r[7] = f2bf(b[3]);
    return r;
}

__device__ __forceinline__ void gload16(const void* g, void* l) {
    __builtin_amdgcn_global_load_lds(
        (const __attribute__((address_space(1))) void*)g,
        (__attribute__((address_space(3))) void*)l, 16, 0, 0);
}

__global__ __launch_bounds__(512)
void locblock_fused(const float* __restrict__ x, const float* __restrict__ w,
                    float* __restrict__ out) {
    // 3 x [ x-tile 16 KB | w-tile 32 KB ] = 144 KB
    __shared__ __align__(16) char smem[3][49152];

    // XCD swizzle: 32 consecutive logical blocks (2 full p's) per XCD ->
    // oh-sibling x reads dedup in the XCD's L2.
    const int hw = blockIdx.x;
    const int lb = (hw & 7) * 32 + (hw >> 3);        // bijective, 256 % 8 == 0
    const int p  = lb >> 4;
    const int q2 = (lb >> 1) & 7;                    // q = 2*q2 + qw
    const int oh = lb & 1;                           // o half (128 o's)

    const int tid  = (int)threadIdx.x;
    const int lane = tid & 63;
    const int wv   = tid >> 6;                       // 0..7
    const int l15  = lane & 15;
    const int kq   = lane >> 4;                      // 0..3
    const int qw   = wv & 1;                         // wave's q within pair
    const int nc   = wv >> 1;                        // wave's o-quarter (32 o)

    // ---- staging sources. x chunk u = c*8 + fr*2 + h (32-B runs);
    //      w chunk u = c*8 + h8 (128-B runs). Source idx = slot ^ (row&15). ----
    const float* xsrc[2];
#pragma unroll
    for (int j = 0; j < 2; ++j) {
        const int id = j * 512 + tid;                // 1024 chunks of 16 B
        const int n = id >> 4, s = id & 15;
        const int u = s ^ (n & 15);
        xsrc[j] = x + (size_t)n * 262144u + (size_t)(u >> 3) * 4096u
                    + (size_t)(4 * p + ((u >> 1) & 3)) * 64u
                    + (size_t)(q2 * 8 + (u & 1) * 4);
    }
    const float* wsrc[4];
#pragma unroll
    for (int j = 0; j < 4; ++j) {
        const int id = j * 512 + tid;                // 2048 chunks of 16 B
        const int ol = id >> 4, s = id & 15;
        const int u = s ^ (ol & 15);
        wsrc[j] = w + (size_t)(oh * 128 + ol) * 262144u + (size_t)(u >> 3) * 4096u
                    + (size_t)p * 256u + (size_t)(q2 * 32) + (size_t)((u & 7) * 4);
    }

    // ---- fragment LDS byte offsets ----
    int aoff[4][2], boff[2][2];
#pragma unroll
    for (int mf = 0; mf < 4; ++mf) {
        const int n = mf * 16 + l15;
        const int v1 = (kq >> 1) * 8 + (kq & 1) * 4 + qw;      // c*8 + fr*2 + h
        aoff[mf][0] = n * 256 + ((v1       ^ l15) * 16);
        aoff[mf][1] = n * 256 + (((v1 + 2) ^ l15) * 16);       // fr+1
    }
#pragma unroll
    for (int nf = 0; nf < 2; ++nf) {
        const int ol = nc * 32 + nf * 16 + l15;
        const int u1 = (kq >> 1) * 8 + qw * 4 + (kq & 1) * 2;  // c*8 + h8
        boff[nf][0] = 16384 + ol * 256 + ((u1       ^ l15) * 16);
        boff[nf][1] = 16384 + ol * 256 + (((u1 + 1) ^ l15) * 16);
    }

    f32x4 acc[4][2];
#pragma unroll
    for (int mf = 0; mf < 4; ++mf)
#pragma unroll
        for (int nf = 0; nf < 2; ++nf)
            acc[mf][nf] = (f32x4){0.f, 0.f, 0.f, 0.f};

    auto stage = [&](int t, int buf) {
        char* base = smem[buf];
        const size_t toff = (size_t)t * 8192u;       // advance 2 c's per step
#pragma unroll
        for (int j = 0; j < 2; ++j)
            gload16(xsrc[j] + toff, base + j * 8192 + wv * 1024);
#pragma unroll
        for (int j = 0; j < 4; ++j)
            gload16(wsrc[j] + toff, base + 16384 + j * 8192 + wv * 1024);
    };

    auto compute = [&](int buf) {
        const char* Lb = smem[buf];
        bf16x8 av[4], bv[2];
#pragma unroll
        for (int mf = 0; mf < 4; ++mf)
            av[mf] = pack8(*(const f32x4*)(Lb + aoff[mf][0]),
                           *(const f32x4*)(Lb + aoff[mf][1]));
#pragma unroll
        for (int nf = 0; nf < 2; ++nf)
            bv[nf] = pack8(*(const f32x4*)(Lb + boff[nf][0]),
                           *(const f32x4*)(Lb + boff[nf][1]));
#pragma unroll
        for (int mf = 0; mf < 4; ++mf)
#pragma unroll
            for (int nf = 0; nf < 2; ++nf)
                acc[mf][nf] = __builtin_amdgcn_mfma_f32_16x16x32_bf16(
                    av[mf], bv[nf], acc[mf][nf], 0, 0, 0);
    };

    // ---- 3-deep pipeline over 32 K-steps (6 loads/thread per stage) ----
    stage(0, 0);
    stage(1, 1);
    stage(2, 2);
#pragma unroll 1
    for (int t = 0; t < 29; ++t) {
        const int buf = t % 3;
        asm volatile("s_waitcnt vmcnt(12)" ::: "memory");  // stage t landed
        __builtin_amdgcn_s_barrier();
        compute(buf);
        asm volatile("s_waitcnt lgkmcnt(0)" ::: "memory"); // reads retired
        __builtin_amdgcn_s_barrier();
        stage(t + 3, buf);
    }
    asm volatile("s_waitcnt vmcnt(12)" ::: "memory");
    __builtin_amdgcn_s_barrier();
    compute(2);                                            // t = 29
    asm volatile("s_waitcnt vmcnt(6)" ::: "memory");
    __builtin_amdgcn_s_barrier();
    compute(0);                                            // t = 30
    asm volatile("s_waitcnt vmcnt(0)" ::: "memory");
    __builtin_amdgcn_s_barrier();
    compute(1);                                            // t = 31

    // ---- epilogue: relu-scale, direct scattered stores to out[n][o][pq] ----
    const float scale = 0.03125f;                    // 1/sqrt(16*64)
    const int pq = p * 16 + q2 * 2 + qw;
#pragma unroll
    for (int mf = 0; mf < 4; ++mf)
#pragma unroll
        for (int nf = 0; nf < 2; ++nf) {
            const int o = oh * 128 + nc * 32 + nf * 16 + l15;
            float* ob = out + (size_t)(mf * 16 + kq * 4) * 65536u
                            + (size_t)o * 256u + pq;
#pragma unroll
            for (int j = 0; j < 4; ++j)
                ob[(size_t)j * 65536u] = fmaxf(acc[mf][nf][j] * scale, 0.0f);
        }
}

extern "C" void kernel_launch(void* const* d_in, const int* in_sizes, int n_in,
                              void* d_out, int out_size, void* d_ws, size_t ws_size,
                              hipStream_t stream) {
    const float* x = (const float*)d_in[0];
    const float* w = (const float*)d_in[1];
    float* out = (float*)d_out;
    locblock_fused<<<dim3(256), dim3(512), 0, stream>>>(x, w, out);
}

// Round 10
// 94.252 us; speedup vs baseline: 1.4347x; 1.0137x over previous
//
#include <hip/hip_runtime.h>

// LocBlock2dNT: x (64,64,64,64) f32, w (256,64,16,16,16) f32
// out (64,256,16,16) f32 = relu( einsum('ncpqf,ocpqf->nopq', patches, w) / 32 )
//
// Block = (p, o-group 32, n-half 32), grid 256, 512 thr. All 16 q per block.
// Staging: both x and w in 1-KB contiguous runs (copy-like DRAM pattern):
//   x[n][c][4p..4p+4][:] = 1 KB ; w[o][c][p][:][:] = 1 KB. One c per K-step,
//   2-deep global_load_lds pipeline (2 x 64 KB LDS), counted vmcnt(8).
// MFMA: 16x16x16 f16 (classic layout: A row=l15,k=kq*4+j; D col=l15,
//   row=kq*4+j). f16 inputs (RNE) are more accurate than bf16.
// Epilogue: LDS transpose (reuse pipeline smem) -> full 64-B-line stores
//   out[n][o][p*16 .. p*16+16).
// x staged 8x (og), w 2x (nh) - dedup'd in XCD L2 via swizzle (all 16
//   sharing blocks of one p land on one XCD).

typedef float    f32x4 __attribute__((ext_vector_type(4)));
typedef _Float16 f16x4 __attribute__((ext_vector_type(4)));

__device__ __forceinline__ void gload16(const void* g, void* l) {
    __builtin_amdgcn_global_load_lds(
        (const __attribute__((address_space(1))) void*)g,
        (__attribute__((address_space(3))) void*)l, 16, 0, 0);
}

__device__ __forceinline__ f16x4 cvt4(f32x4 v) {
    f16x4 r;
    r[0] = (_Float16)v[0]; r[1] = (_Float16)v[1];
    r[2] = (_Float16)v[2]; r[3] = (_Float16)v[3];
    return r;
}

__global__ __launch_bounds__(512)
void locblock_fused(const float* __restrict__ x, const float* __restrict__ w,
                    float* __restrict__ out) {
    // 2 pipeline bufs x [ x-tile 32 KB | w-tile 32 KB ]; epilogue overlays.
    __shared__ __align__(16) char smem[131072];

    // XCD swizzle: 32 consecutive logical blocks (= 2 full p's, each p's 16
    // sharing blocks) per XCD -> x/w redundancy is L2-served.
    const int hw = blockIdx.x;
    const int lb = (hw & 7) * 32 + (hw >> 3);        // bijective, 256 % 8 == 0
    const int p  = lb >> 4;                          // 0..15
    const int og = (lb >> 1) & 7;                    // o-group (32 o's)
    const int nh = lb & 1;                           // n-half  (32 n's)

    const int tid  = (int)threadIdx.x;
    const int lane = tid & 63;
    const int wv   = tid >> 6;                       // 0..7 (also: q-pair)
    const int l15  = lane & 15;
    const int kq   = lane >> 4;                      // 0..3

    // ---- staging sources: per instr j, the wave reads ONE 1-KB run.
    // Chunk (16 B) u within a run stored at LDS slot s=lane; u = lane ^ wv
    // (XOR-swizzle on SOURCE; row&7 == wv for rows j*8+wv).
    const int u = lane ^ wv;
    const float* xsrc[4];
    const float* wsrc[4];
#pragma unroll
    for (int j = 0; j < 4; ++j) {
        xsrc[j] = x + (size_t)(nh * 32 + j * 8 + wv) * 262144u
                    + (size_t)p * 256u + (size_t)(u * 4);
        wsrc[j] = w + (size_t)(og * 32 + j * 8 + wv) * 262144u
                    + (size_t)p * 256u + (size_t)(u * 4);
    }

    // ---- fragment LDS byte offsets (within a 64-KB buf) ----
    // A (x): row n_l = mf*16+l15, chunk u = kq*16 + q  (fr=kq, fc=j)
    // B (w): row o_l = nf*16+l15, chunk u = q*4 + kq   (k = kq*4+j)
    int aoff[2][2], boff[2][2];                      // [qi][mf], [qi][nf]
#pragma unroll
    for (int qi = 0; qi < 2; ++qi) {
        const int q = wv * 2 + qi;
#pragma unroll
        for (int mf = 0; mf < 2; ++mf)
            aoff[qi][mf] = (mf * 16 + l15) * 1024
                         + (((kq * 16 + q) ^ (l15 & 7)) * 16);
#pragma unroll
        for (int nf = 0; nf < 2; ++nf)
            boff[qi][nf] = 32768 + (nf * 16 + l15) * 1024
                         + (((q * 4 + kq) ^ (l15 & 7)) * 16);
    }

    f32x4 acc[2][2][2];                              // [qi][mf][nf]
#pragma unroll
    for (int qi = 0; qi < 2; ++qi)
#pragma unroll
        for (int mf = 0; mf < 2; ++mf)
#pragma unroll
            for (int nf = 0; nf < 2; ++nf)
                acc[qi][mf][nf] = (f32x4){0.f, 0.f, 0.f, 0.f};

    auto stage = [&](int c) {
        char* base = smem + (size_t)(c & 1) * 65536u;
        const size_t coff = (size_t)c * 4096u;
#pragma unroll
        for (int j = 0; j < 4; ++j)
            gload16(xsrc[j] + coff, base + (j * 8 + wv) * 1024);
#pragma unroll
        for (int j = 0; j < 4; ++j)
            gload16(wsrc[j] + coff, base + 32768 + (j * 8 + wv) * 1024);
    };

    auto compute = [&](int c) {
        const char* base = smem + (size_t)(c & 1) * 65536u;
#pragma unroll
        for (int qi = 0; qi < 2; ++qi) {
            f16x4 av[2], bv[2];
#pragma unroll
            for (int mf = 0; mf < 2; ++mf)
                av[mf] = cvt4(*(const f32x4*)(base + aoff[qi][mf]));
#pragma unroll
            for (int nf = 0; nf < 2; ++nf)
                bv[nf] = cvt4(*(const f32x4*)(base + boff[qi][nf]));
#pragma unroll
            for (int mf = 0; mf < 2; ++mf)
#pragma unroll
                for (int nf = 0; nf < 2; ++nf)
                    acc[qi][mf][nf] = __builtin_amdgcn_mfma_f32_16x16x16f16(
                        av[mf], bv[nf], acc[qi][mf][nf], 0, 0, 0);
        }
    };

    // ---- 2-deep pipeline over 64 c-steps (8 loads/thread per stage) ----
    stage(0);
    stage(1);
#pragma unroll 1
    for (int c = 0; c < 62; ++c) {
        asm volatile("s_waitcnt vmcnt(8)" ::: "memory");   // stage c landed
        __builtin_amdgcn_s_barrier();
        compute(c);
        asm volatile("s_waitcnt lgkmcnt(0)" ::: "memory"); // reads retired
        __builtin_amdgcn_s_barrier();
        stage(c + 2);
    }
    asm volatile("s_waitcnt vmcnt(8)" ::: "memory");
    __builtin_amdgcn_s_barrier();
    compute(62);
    asm volatile("s_waitcnt vmcnt(0)" ::: "memory");
    __builtin_amdgcn_s_barrier();
    compute(63);

    __syncthreads();                                 // smem reuse fence

    // ---- epilogue phase 1: acc -> T[q][o][n], strides (1152,36,1) words ----
    float* T = (float*)smem;                         // 16*1152*4 = 73.7 KB
    const float scale = 0.03125f;                    // 1/sqrt(16*64)
#pragma unroll
    for (int qi = 0; qi < 2; ++qi) {
        const int q = wv * 2 + qi;
#pragma unroll
        for (int mf = 0; mf < 2; ++mf)
#pragma unroll
            for (int nf = 0; nf < 2; ++nf) {
                f32x4 r;
#pragma unroll
                for (int j = 0; j < 4; ++j)
                    r[j] = fmaxf(acc[qi][mf][nf][j] * scale, 0.0f);
                // D layout: col=l15 (o), row=kq*4+j (n)
                *(f32x4*)(T + q * 1152 + (nf * 16 + l15) * 36
                            + mf * 16 + kq * 4) = r;
            }
    }
    __syncthreads();

    // ---- epilogue phase 2: T -> out[n][o][p*16+0..15], 64-B lines ----
#pragma unroll
    for (int i = 0; i < 8; ++i) {
        const int item = i * 512 + tid;              // 4096 f32x4 items
        const int o  = item >> 7;                    // 0..31
        const int rm = item & 127;
        const int n  = rm >> 2;                      // 0..31
        const int qg = rm & 3;                       // pq quad
        f32x4 r;
#pragma unroll
        for (int s = 0; s < 4; ++s)
            r[s] = T[(qg * 4 + s) * 1152 + o * 36 + n];
        *(f32x4*)(out + (size_t)(nh * 32 + n) * 65536u
                      + (size_t)(og * 32 + o) * 256u
                      + (size_t)(p * 16 + qg * 4)) = r;
    }
}

extern "C" void kernel_launch(void* const* d_in, const int* in_sizes, int n_in,
                              void* d_out, int out_size, void* d_ws, size_t ws_size,
                              hipStream_t stream) {
    const float* x = (const float*)d_in[0];
    const float* w = (const float*)d_in[1];
    float* out = (float*)d_out;
    locblock_fused<<<dim3(256), dim3(512), 0, stream>>>(x, w, out);
}